// Round 2
// baseline (1534.303 us; speedup 1.0000x reference)
//
#include <hip/hip_runtime.h>
#include <hip/hip_fp16.h>

#define N_NODES 16384
#define SEQ_L   8
#define DIM_D   256
#define DIM_H   256
#define DIM_R   64

typedef float    f32x4 __attribute__((ext_vector_type(4)));
typedef _Float16 f16x8 __attribute__((ext_vector_type(8)));
typedef _Float16 f16x4 __attribute__((ext_vector_type(4)));

__device__ __forceinline__ float fsig(float x) {
    return __builtin_amdgcn_rcpf(1.f + __expf(-x));
}
__device__ __forceinline__ float ftanh(float x) {
    return 1.f - 2.f * __builtin_amdgcn_rcpf(1.f + __expf(2.f * x));
}

// ---------------------------------------------------------------------------
// prep: convert + PACK weights into MFMA B-fragment order.
// Packed layout for W[C rows][K cols] (C = gemm output cols, K = reduction):
//   P[((colgrp*KS + ks)*64 + lane)*8 + j] = W[colgrp*16 + (lane&15)][ks*32 + (lane>>4)*8 + j]
// so a wave's B-load for (colgrp, ks) is 64 lanes * contiguous 16B = 1KB burst.
// ---------------------------------------------------------------------------
__device__ __forceinline__ void pack_w(const float* __restrict__ W, _Float16* __restrict__ P,
                                       int n_colgrp, int n_ks, int Kdim,
                                       int t0, int stride) {
    const int total = n_colgrp * n_ks * 64;
    for (int i = t0; i < total; i += stride) {
        int colgrp = i / (n_ks * 64);
        int rem    = i - colgrp * (n_ks * 64);
        int ks     = rem >> 6;
        int lane   = rem & 63;
        int srow   = colgrp * 16 + (lane & 15);
        int sk     = ks * 32 + (lane >> 4) * 8;
        const float* s = W + (size_t)srow * Kdim + sk;
        f32x4 v0 = *(const f32x4*)s;
        f32x4 v1 = *(const f32x4*)(s + 4);
        f16x8 h;
        h[0] = (_Float16)v0[0]; h[1] = (_Float16)v0[1];
        h[2] = (_Float16)v0[2]; h[3] = (_Float16)v0[3];
        h[4] = (_Float16)v1[0]; h[5] = (_Float16)v1[1];
        h[6] = (_Float16)v1[2]; h[7] = (_Float16)v1[3];
        *(f16x8*)&P[(size_t)i * 8] = h;
    }
}

__global__ void prep_kernel(const float* __restrict__ Wih_l, const float* __restrict__ Whh_l,
                            const float* __restrict__ Wih_r, const float* __restrict__ Whh_r,
                            const float* __restrict__ Wenc,  const float* __restrict__ rel,
                            _Float16* __restrict__ pih_l, _Float16* __restrict__ phh_l,
                            _Float16* __restrict__ pih_r, _Float16* __restrict__ phh_r,
                            _Float16* __restrict__ penc,  _Float16* __restrict__ rel16) {
    const int stride = gridDim.x * blockDim.x;
    const int t0 = blockIdx.x * blockDim.x + threadIdx.x;
    pack_w(Wih_l, pih_l, 64, 8, 256, t0, stride);
    pack_w(Whh_l, phh_l, 64, 8, 256, t0, stride);
    pack_w(Wih_r, pih_r, 64, 8, 256, t0, stride);
    pack_w(Whh_r, phh_r, 64, 8, 256, t0, stride);
    pack_w(Wenc,  penc,  16, 18, 576, t0, stride);
    // rel: plain f32 -> f16, rowmajor
    const int nq = (N_NODES * DIM_R) / 8;
    for (int i = t0; i < nq; i += stride) {
        f32x4 v0 = *(const f32x4*)(rel + (size_t)i * 8);
        f32x4 v1 = *(const f32x4*)(rel + (size_t)i * 8 + 4);
        f16x8 h;
        h[0] = (_Float16)v0[0]; h[1] = (_Float16)v0[1];
        h[2] = (_Float16)v0[2]; h[3] = (_Float16)v0[3];
        h[4] = (_Float16)v1[0]; h[5] = (_Float16)v1[1];
        h[6] = (_Float16)v1[2]; h[7] = (_Float16)v1[3];
        *(f16x8*)&rel16[(size_t)i * 8] = h;
    }
}

// ---------------------------------------------------------------------------
// fused LSTM, 64 nodes/block, 512 threads = 8 waves.
// Wave w owns hidden units [w*32, w*32+32) for all 4 gates.
// acc[rt 0..3][g 0..3][ht 0..1] f32x4 = 128 regs (AGPR), cst 32 (f32 cell state).
// ---------------------------------------------------------------------------
__global__ __launch_bounds__(512, 2) void lstm_kernel(
    const float* __restrict__ left, const float* __restrict__ right,
    const _Float16* __restrict__ pih_l, const _Float16* __restrict__ phh_l,
    const _Float16* __restrict__ pih_r, const _Float16* __restrict__ phh_r,
    const float* __restrict__ bih_l, const float* __restrict__ bhh_l,
    const float* __restrict__ bih_r, const float* __restrict__ bhh_r,
    _Float16* __restrict__ hl_out, _Float16* __restrict__ hr_out) {

    const int side = blockIdx.y;
    const float*    chain = side ? right : left;
    const _Float16* Pih   = side ? pih_r : pih_l;
    const _Float16* Phh   = side ? phh_r : phh_l;
    const float*    bih   = side ? bih_r : bih_l;
    const float*    bhh   = side ? bhh_r : bhh_l;
    _Float16*       hout  = side ? hr_out : hl_out;

    __shared__ _Float16 lds_x[64 * 256] __attribute__((aligned(16)));
    __shared__ _Float16 lds_h[64 * 256] __attribute__((aligned(16)));

    const int tid  = threadIdx.x;
    const int lane = tid & 63;
    const int wave = tid >> 6;        // 0..7
    const int l15  = lane & 15;
    const int l4   = lane >> 4;       // 0..3
    const int klb  = l4 * 8;
    const int node0 = blockIdx.x * 64;
    const int hid0  = wave * 32;

    const f32x4 FZ = {0.f, 0.f, 0.f, 0.f};

    // fused bias per owned col
    float bias[4][2];
#pragma unroll
    for (int g = 0; g < 4; ++g)
#pragma unroll
        for (int ht = 0; ht < 2; ++ht) {
            int col = g * 256 + hid0 + ht * 16 + l15;
            bias[g][ht] = bih[col] + bhh[col];
        }

    // packed-B per-lane base (wave-uniform colgrp base + lane*8)
    const int cg0 = wave * 2;   // colgrp for (g, ht) = g*16 + cg0 + ht

    f32x4 acc[4][4][2];
    f32x4 cst[4][2];
#pragma unroll
    for (int rt = 0; rt < 4; ++rt)
#pragma unroll
        for (int ht = 0; ht < 2; ++ht) cst[rt][ht] = FZ;

    auto do_gemm = [&](const _Float16* lds, const _Float16* P) {
#pragma unroll
        for (int ks = 0; ks < 8; ++ks) {
            const int kk = ks * 32 + klb;
            f16x8 a[4];
#pragma unroll
            for (int rt = 0; rt < 4; ++rt) {
                int row = rt * 16 + l15;
                int off = row * 256 + (kk ^ ((row & 7) << 3));
                a[rt] = *(const f16x8*)&lds[off];
            }
#pragma unroll
            for (int g = 0; g < 4; ++g)
#pragma unroll
                for (int ht = 0; ht < 2; ++ht) {
                    f16x8 b = *(const f16x8*)&P[(((g * 16 + cg0 + ht) * 8 + ks) << 9) + (lane << 3)];
#pragma unroll
                    for (int rt = 0; rt < 4; ++rt)
                        acc[rt][g][ht] = __builtin_amdgcn_mfma_f32_16x16x32_f16(
                            a[rt], b, acc[rt][g][ht], 0, 0, 0);
                }
        }
    };

#pragma unroll 1
    for (int t = 0; t < SEQ_L; ++t) {
        // stage x_t: nontemporal f32x4 -> f16 swizzled LDS
#pragma unroll
        for (int it = 0; it < 8; ++it) {
            int e4  = it * 512 + tid;
            int row = e4 >> 6;
            int kq  = (e4 & 63) << 2;
            f32x4 v = __builtin_nontemporal_load((const f32x4*)(chain +
                      (size_t)(node0 + row) * (SEQ_L * DIM_D) + t * DIM_D + kq));
            f16x4 h4;
            h4[0] = (_Float16)v[0]; h4[1] = (_Float16)v[1];
            h4[2] = (_Float16)v[2]; h4[3] = (_Float16)v[3];
            int idx = row * 256 + (kq ^ ((row & 7) << 3));
            *(f16x4*)&lds_x[idx] = h4;
        }
        __syncthreads();   // x_t staged; h(t-1) writes visible

#pragma unroll
        for (int rt = 0; rt < 4; ++rt)
#pragma unroll
            for (int g = 0; g < 4; ++g)
#pragma unroll
                for (int ht = 0; ht < 2; ++ht) acc[rt][g][ht] = FZ;

        do_gemm(lds_x, Pih);
        if (t > 0) do_gemm(lds_h, Phh);
        __syncthreads();   // LDS reads done before lds_h overwrite

        // gates i,f,g,o
#pragma unroll
        for (int rt = 0; rt < 4; ++rt)
#pragma unroll
            for (int ht = 0; ht < 2; ++ht)
#pragma unroll
                for (int r = 0; r < 4; ++r) {
                    float gi = acc[rt][0][ht][r] + bias[0][ht];
                    float gf = acc[rt][1][ht][r] + bias[1][ht];
                    float gg = acc[rt][2][ht][r] + bias[2][ht];
                    float go = acc[rt][3][ht][r] + bias[3][ht];
                    float ii = fsig(gi), ff = fsig(gf);
                    float gt = ftanh(gg), oo = fsig(go);
                    float c = ff * cst[rt][ht][r] + ii * gt;
                    cst[rt][ht][r] = c;
                    float h = oo * ftanh(c);
                    int rowl = rt * 16 + l4 * 4 + r;
                    int hid  = hid0 + ht * 16 + l15;
                    lds_h[rowl * 256 + (hid ^ ((rowl & 7) << 3))] = (_Float16)h;
                }
    }

    // coalesced copy-out of h(7) from LDS
    __syncthreads();
    {
        int row = tid >> 3;            // 0..63
        int seg = (tid & 7) * 32;      // 8 segs of 32 hid
        _Float16* dst = hout + (size_t)(node0 + row) * 256 + seg;
        int sw = (row & 7) << 3;
#pragma unroll
        for (int j = 0; j < 4; ++j) {
            f16x8 v = *(const f16x8*)&lds_h[row * 256 + ((seg + j * 8) ^ sw)];
            __builtin_nontemporal_store(v, (f16x8*)(dst + j * 8));
        }
    }
}

// ---------------------------------------------------------------------------
// encoder: tanh([hl|hr|rel] @ Wenc^T + benc), packed Wenc
// ---------------------------------------------------------------------------
__global__ __launch_bounds__(256, 2) void enc_kernel(
    const _Float16* __restrict__ hl, const _Float16* __restrict__ hr,
    const _Float16* __restrict__ rel16, const _Float16* __restrict__ penc,
    const float* __restrict__ benc, float* __restrict__ out) {

    const int tid  = threadIdx.x;
    const int lane = tid & 63;
    const int wave = tid >> 6;    // 0..3
    const int l15  = lane & 15;
    const int l4   = lane >> 4;
    const int klb  = l4 * 8;
    const int row0 = blockIdx.x * 64;
    const int colw = wave * 64;

    const f32x4 FZ = {0.f, 0.f, 0.f, 0.f};
    f32x4 acc[4][4];
#pragma unroll
    for (int rt = 0; rt < 4; ++rt)
#pragma unroll
        for (int ct = 0; ct < 4; ++ct) acc[rt][ct] = FZ;

    float bce[4];
#pragma unroll
    for (int ct = 0; ct < 4; ++ct) bce[ct] = benc[colw + ct * 16 + l15];

    for (int ks = 0; ks < 18; ++ks) {   // K = 576
        const int kk = ks * 32 + klb;
        f16x8 a[4];
#pragma unroll
        for (int rt = 0; rt < 4; ++rt) {
            int row = row0 + rt * 16 + l15;
            const _Float16* p;
            if (ks < 8)       p = hl    + (size_t)row * 256 + kk;
            else if (ks < 16) p = hr    + (size_t)row * 256 + (kk - 256);
            else              p = rel16 + (size_t)row * 64  + (kk - 512);
            a[rt] = *(const f16x8*)p;
        }
#pragma unroll
        for (int ct = 0; ct < 4; ++ct) {
            f16x8 b = *(const f16x8*)&penc[((((wave * 4 + ct) * 18 + ks)) << 9) + (lane << 3)];
#pragma unroll
            for (int rt = 0; rt < 4; ++rt)
                acc[rt][ct] = __builtin_amdgcn_mfma_f32_16x16x32_f16(
                    a[rt], b, acc[rt][ct], 0, 0, 0);
        }
    }

#pragma unroll
    for (int rt = 0; rt < 4; ++rt)
#pragma unroll
        for (int ct = 0; ct < 4; ++ct)
#pragma unroll
            for (int r = 0; r < 4; ++r) {
                int row = row0 + rt * 16 + l4 * 4 + r;
                int col = colw + ct * 16 + l15;
                out[(size_t)row * 256 + col] = ftanh(acc[rt][ct][r] + bce[ct]);
            }
}

extern "C" void kernel_launch(void* const* d_in, const int* in_sizes, int n_in,
                              void* d_out, int out_size, void* d_ws, size_t ws_size,
                              hipStream_t stream) {
    const float* left  = (const float*)d_in[0];
    const float* right = (const float*)d_in[1];
    const float* rel   = (const float*)d_in[2];
    const float* Wih_l = (const float*)d_in[3];
    const float* Whh_l = (const float*)d_in[4];
    const float* bih_l = (const float*)d_in[5];
    const float* bhh_l = (const float*)d_in[6];
    const float* Wih_r = (const float*)d_in[7];
    const float* Whh_r = (const float*)d_in[8];
    const float* bih_r = (const float*)d_in[9];
    const float* bhh_r = (const float*)d_in[10];
    const float* Wenc  = (const float*)d_in[11];
    const float* benc  = (const float*)d_in[12];
    float* out = (float*)d_out;

    char* ws = (char*)d_ws;
    _Float16* pih_l = (_Float16*)(ws);
    _Float16* phh_l = (_Float16*)(ws + 512 * 1024);
    _Float16* pih_r = (_Float16*)(ws + 1024 * 1024);
    _Float16* phh_r = (_Float16*)(ws + 1536 * 1024);
    _Float16* penc  = (_Float16*)(ws + 2048 * 1024);
    _Float16* rel16 = (_Float16*)(ws + 2560 * 1024);
    _Float16* hl16  = (_Float16*)(ws + 4608 * 1024);
    _Float16* hr16  = (_Float16*)(ws + 4608 * 1024 + 8192 * 1024);
    (void)in_sizes; (void)n_in; (void)out_size; (void)ws_size;

    hipLaunchKernelGGL(prep_kernel, dim3(512), dim3(256), 0, stream,
                       Wih_l, Whh_l, Wih_r, Whh_r, Wenc, rel,
                       pih_l, phh_l, pih_r, phh_r, penc, rel16);

    hipLaunchKernelGGL(lstm_kernel, dim3(N_NODES / 64, 2), dim3(512), 0, stream,
                       left, right, pih_l, phh_l, pih_r, phh_r,
                       bih_l, bhh_l, bih_r, bhh_r, hl16, hr16);

    hipLaunchKernelGGL(enc_kernel, dim3(N_NODES / 64), dim3(256), 0, stream,
                       hl16, hr16, rel16, penc, benc, out);
}

// Round 3
// 1400.650 us; speedup vs baseline: 1.0954x; 1.0954x over previous
//
#include <hip/hip_runtime.h>
#include <hip/hip_fp16.h>

#define N_NODES 16384
#define SEQ_L   8
#define DIM_D   256
#define DIM_H   256
#define DIM_R   64

typedef float    f32x4 __attribute__((ext_vector_type(4)));
typedef _Float16 f16x8 __attribute__((ext_vector_type(8)));
typedef _Float16 f16x4 __attribute__((ext_vector_type(4)));

__device__ __forceinline__ float fsig(float x) {
    return __builtin_amdgcn_rcpf(1.f + __expf(-x));
}
__device__ __forceinline__ float ftanh(float x) {
    return 1.f - 2.f * __builtin_amdgcn_rcpf(1.f + __expf(2.f * x));
}

// ---------------------------------------------------------------------------
// prep: pack weights WAVE-MAJOR so the consumer's B-load is
//   Pw = P + wave*32768;  b = Pw[frag*512 + lane*8]   (frag = (g*2+ht)*8+ks)
// i.e. SGPR base + compile-time imm + lane*16B. One contiguous 1KB burst/frag.
// ---------------------------------------------------------------------------
__global__ void prep_kernel(const float* __restrict__ Wih_l, const float* __restrict__ Whh_l,
                            const float* __restrict__ Wih_r, const float* __restrict__ Whh_r,
                            const float* __restrict__ Wenc,  const float* __restrict__ rel,
                            _Float16* __restrict__ pih_l, _Float16* __restrict__ phh_l,
                            _Float16* __restrict__ pih_r, _Float16* __restrict__ phh_r,
                            _Float16* __restrict__ penc,  _Float16* __restrict__ rel16) {
    const int stride = gridDim.x * blockDim.x;
    const int t0 = blockIdx.x * blockDim.x + threadIdx.x;

    // lstm weights: 8 waves x 64 frags x 64 lanes, W is [1024][256]
    const float* SW[4] = {Wih_l, Whh_l, Wih_r, Whh_r};
    _Float16*    DW[4] = {pih_l, phh_l, pih_r, phh_r};
    for (int m = 0; m < 4; ++m) {
        const float* W = SW[m];
        _Float16*    P = DW[m];
        for (int i8 = t0; i8 < 32768; i8 += stride) {
            int w    = i8 >> 12;          // wave 0..7
            int rem  = i8 & 4095;
            int f    = rem >> 6;          // frag 0..63 = g*16 + ht*8 + ks
            int lane = rem & 63;
            int g    = f >> 4;
            int ht   = (f >> 3) & 1;
            int ks   = f & 7;
            int col  = g * 256 + w * 32 + ht * 16 + (lane & 15);
            int k    = ks * 32 + (lane >> 4) * 8;
            const float* s = W + (size_t)col * 256 + k;
            f32x4 v0 = *(const f32x4*)s;
            f32x4 v1 = *(const f32x4*)(s + 4);
            f16x8 h;
            h[0] = (_Float16)v0[0]; h[1] = (_Float16)v0[1];
            h[2] = (_Float16)v0[2]; h[3] = (_Float16)v0[3];
            h[4] = (_Float16)v1[0]; h[5] = (_Float16)v1[1];
            h[6] = (_Float16)v1[2]; h[7] = (_Float16)v1[3];
            *(f16x8*)&P[(size_t)i8 * 8] = h;
        }
    }

    // enc weights: 4 waves x 72 frags (ct 0..3, ks 0..17), Wenc is [256][576]
    for (int i8 = t0; i8 < 18432; i8 += stride) {
        int w    = i8 / 4608;
        int rem  = i8 - w * 4608;
        int f    = rem >> 6;              // 0..71 = ct*18 + ks
        int lane = rem & 63;
        int ct   = f / 18;
        int ks   = f - ct * 18;
        int col  = w * 64 + ct * 16 + (lane & 15);
        int k    = ks * 32 + (lane >> 4) * 8;
        const float* s = Wenc + (size_t)col * 576 + k;
        f32x4 v0 = *(const f32x4*)s;
        f32x4 v1 = *(const f32x4*)(s + 4);
        f16x8 h;
        h[0] = (_Float16)v0[0]; h[1] = (_Float16)v0[1];
        h[2] = (_Float16)v0[2]; h[3] = (_Float16)v0[3];
        h[4] = (_Float16)v1[0]; h[5] = (_Float16)v1[1];
        h[6] = (_Float16)v1[2]; h[7] = (_Float16)v1[3];
        *(f16x8*)&penc[(size_t)i8 * 8] = h;
    }

    // rel: f32 -> f16 rowmajor
    const int nq = (N_NODES * DIM_R) / 8;
    for (int i = t0; i < nq; i += stride) {
        f32x4 v0 = *(const f32x4*)(rel + (size_t)i * 8);
        f32x4 v1 = *(const f32x4*)(rel + (size_t)i * 8 + 4);
        f16x8 h;
        h[0] = (_Float16)v0[0]; h[1] = (_Float16)v0[1];
        h[2] = (_Float16)v0[2]; h[3] = (_Float16)v0[3];
        h[4] = (_Float16)v1[0]; h[5] = (_Float16)v1[1];
        h[6] = (_Float16)v1[2]; h[7] = (_Float16)v1[3];
        *(f16x8*)&rel16[(size_t)i * 8] = h;
    }
}

// ---------------------------------------------------------------------------
// fused LSTM, 64 nodes/block, 512 threads = 8 waves.
// LDS: one array, x at elem 0, h at elem 16384. Element (row,k) stored at
// row*256 + (k ^ ((row&3)<<3)) -- XOR bits 3..4 only, disjoint from ks*32,
// so A-reads fold to vaddr(rt) + imm(base + ks*64).
// ---------------------------------------------------------------------------
__global__ __launch_bounds__(512, 2) void lstm_kernel(
    const float* __restrict__ left, const float* __restrict__ right,
    const _Float16* __restrict__ pih_l, const _Float16* __restrict__ phh_l,
    const _Float16* __restrict__ pih_r, const _Float16* __restrict__ phh_r,
    const float* __restrict__ bih_l, const float* __restrict__ bhh_l,
    const float* __restrict__ bih_r, const float* __restrict__ bhh_r,
    _Float16* __restrict__ hl_out, _Float16* __restrict__ hr_out) {

    const int side = blockIdx.y;
    const float*    chain = side ? right : left;
    const float*    bih   = side ? bih_r : bih_l;
    const float*    bhh   = side ? bhh_r : bhh_l;
    _Float16*       hout  = side ? hr_out : hl_out;

    __shared__ _Float16 lds[2 * 64 * 256] __attribute__((aligned(16)));

    const int tid  = threadIdx.x;
    const int lane = tid & 63;
    const int wave = tid >> 6;        // 0..7
    const int wu   = __builtin_amdgcn_readfirstlane(wave);
    const int l15  = lane & 15;
    const int l4   = lane >> 4;       // 0..3
    const int klb  = l4 * 8;
    const int node0 = blockIdx.x * 64;
    const int hid0  = wu * 32;

    // wave-uniform packed-weight bases (SGPR)
    const _Float16* Pih = (side ? pih_r : pih_l) + wu * 32768;
    const _Float16* Phh = (side ? phh_r : phh_l) + wu * 32768;

    const f32x4 FZ = {0.f, 0.f, 0.f, 0.f};

    float bias[4][2];
#pragma unroll
    for (int g = 0; g < 4; ++g)
#pragma unroll
        for (int ht = 0; ht < 2; ++ht) {
            int col = g * 256 + hid0 + ht * 16 + l15;
            bias[g][ht] = bih[col] + bhh[col];
        }

    f32x4 acc[4][4][2];
    f32x4 cst[4][2];
#pragma unroll
    for (int rt = 0; rt < 4; ++rt)
#pragma unroll
        for (int ht = 0; ht < 2; ++ht) cst[rt][ht] = FZ;

    // A-read element base per rowtile (vaddr); ks contributes imm only.
    int abase[4];
#pragma unroll
    for (int rt = 0; rt < 4; ++rt) {
        int row = rt * 16 + l15;
        abase[rt] = row * 256 + (klb ^ ((row & 3) << 3));
    }

    auto do_gemm = [&](const int lds_ofs, const _Float16* Pw) {
#pragma unroll
        for (int ks = 0; ks < 8; ++ks) {
            f16x8 a[4];
#pragma unroll
            for (int rt = 0; rt < 4; ++rt)
                a[rt] = *(const f16x8*)&lds[lds_ofs + abase[rt] + ks * 32];
            f16x8 b[8];
#pragma unroll
            for (int f = 0; f < 8; ++f)
                b[f] = *(const f16x8*)&Pw[(f * 8 + ks) * 512 + (lane << 3)];
#pragma unroll
            for (int g = 0; g < 4; ++g)
#pragma unroll
                for (int ht = 0; ht < 2; ++ht)
#pragma unroll
                    for (int rt = 0; rt < 4; ++rt)
                        acc[rt][g][ht] = __builtin_amdgcn_mfma_f32_16x16x32_f16(
                            a[rt], b[g * 2 + ht], acc[rt][g][ht], 0, 0, 0);
        }
    };

#pragma unroll 1
    for (int t = 0; t < SEQ_L; ++t) {
        // stage x_t: nontemporal f32x4 -> f16, swizzled LDS
#pragma unroll
        for (int it = 0; it < 8; ++it) {
            int e4  = it * 512 + tid;
            int row = e4 >> 6;
            int kq  = (e4 & 63) << 2;
            f32x4 v = __builtin_nontemporal_load((const f32x4*)(chain +
                      (size_t)(node0 + row) * (SEQ_L * DIM_D) + t * DIM_D + kq));
            f16x4 h4;
            h4[0] = (_Float16)v[0]; h4[1] = (_Float16)v[1];
            h4[2] = (_Float16)v[2]; h4[3] = (_Float16)v[3];
            *(f16x4*)&lds[row * 256 + (kq ^ ((row & 3) << 3))] = h4;
        }
        __syncthreads();   // x_t staged; h(t-1) writes visible

#pragma unroll
        for (int rt = 0; rt < 4; ++rt)
#pragma unroll
            for (int g = 0; g < 4; ++g)
#pragma unroll
                for (int ht = 0; ht < 2; ++ht) acc[rt][g][ht] = FZ;

        do_gemm(0, Pih);
        if (t > 0) do_gemm(16384, Phh);
        __syncthreads();   // LDS reads done before lds_h overwrite

        // gates i,f,g,o
#pragma unroll
        for (int rt = 0; rt < 4; ++rt)
#pragma unroll
            for (int ht = 0; ht < 2; ++ht)
#pragma unroll
                for (int r = 0; r < 4; ++r) {
                    float gi = acc[rt][0][ht][r] + bias[0][ht];
                    float gf = acc[rt][1][ht][r] + bias[1][ht];
                    float gg = acc[rt][2][ht][r] + bias[2][ht];
                    float go = acc[rt][3][ht][r] + bias[3][ht];
                    float ii = fsig(gi), ff = fsig(gf);
                    float gt = ftanh(gg), oo = fsig(go);
                    float c = ff * cst[rt][ht][r] + ii * gt;
                    cst[rt][ht][r] = c;
                    float h = oo * ftanh(c);
                    int rowl = rt * 16 + l4 * 4 + r;
                    int hid  = hid0 + ht * 16 + l15;
                    lds[16384 + rowl * 256 + (hid ^ ((rowl & 3) << 3))] = (_Float16)h;
                }
    }

    // coalesced copy-out of h(7)
    __syncthreads();
    {
        int row = tid >> 3;
        int seg = (tid & 7) * 32;
        _Float16* dst = hout + (size_t)(node0 + row) * 256 + seg;
        int sw = (row & 3) << 3;
#pragma unroll
        for (int j = 0; j < 4; ++j) {
            f16x8 v = *(const f16x8*)&lds[16384 + row * 256 + ((seg + j * 8) ^ sw)];
            __builtin_nontemporal_store(v, (f16x8*)(dst + j * 8));
        }
    }
}

// ---------------------------------------------------------------------------
// encoder: tanh([hl|hr|rel] @ Wenc^T + benc), wave-major packed Wenc
// ---------------------------------------------------------------------------
__global__ __launch_bounds__(256, 2) void enc_kernel(
    const _Float16* __restrict__ hl, const _Float16* __restrict__ hr,
    const _Float16* __restrict__ rel16, const _Float16* __restrict__ penc,
    const float* __restrict__ benc, float* __restrict__ out) {

    const int tid  = threadIdx.x;
    const int lane = tid & 63;
    const int wave = tid >> 6;    // 0..3
    const int wu   = __builtin_amdgcn_readfirstlane(wave);
    const int l15  = lane & 15;
    const int l4   = lane >> 4;
    const int klb  = l4 * 8;
    const int row0 = blockIdx.x * 64;
    const int colw = wu * 64;

    const _Float16* Pw = penc + wu * 36864;

    const f32x4 FZ = {0.f, 0.f, 0.f, 0.f};
    f32x4 acc[4][4];
#pragma unroll
    for (int rt = 0; rt < 4; ++rt)
#pragma unroll
        for (int ct = 0; ct < 4; ++ct) acc[rt][ct] = FZ;

    float bce[4];
#pragma unroll
    for (int ct = 0; ct < 4; ++ct) bce[ct] = benc[colw + ct * 16 + l15];

    for (int ks = 0; ks < 18; ++ks) {   // K = 576
        const int kk = ks * 32 + klb;
        f16x8 a[4];
#pragma unroll
        for (int rt = 0; rt < 4; ++rt) {
            int row = row0 + rt * 16 + l15;
            const _Float16* p;
            if (ks < 8)       p = hl    + (size_t)row * 256 + kk;
            else if (ks < 16) p = hr    + (size_t)row * 256 + (kk - 256);
            else              p = rel16 + (size_t)row * 64  + (kk - 512);
            a[rt] = *(const f16x8*)p;
        }
#pragma unroll
        for (int ct = 0; ct < 4; ++ct) {
            f16x8 b = *(const f16x8*)&Pw[(ct * 18 + ks) * 512 + (lane << 3)];
#pragma unroll
            for (int rt = 0; rt < 4; ++rt)
                acc[rt][ct] = __builtin_amdgcn_mfma_f32_16x16x32_f16(
                    a[rt], b, acc[rt][ct], 0, 0, 0);
        }
    }

#pragma unroll
    for (int rt = 0; rt < 4; ++rt)
#pragma unroll
        for (int ct = 0; ct < 4; ++ct)
#pragma unroll
            for (int r = 0; r < 4; ++r) {
                int row = row0 + rt * 16 + l4 * 4 + r;
                int col = colw + ct * 16 + l15;
                out[(size_t)row * 256 + col] = ftanh(acc[rt][ct][r] + bce[ct]);
            }
}

extern "C" void kernel_launch(void* const* d_in, const int* in_sizes, int n_in,
                              void* d_out, int out_size, void* d_ws, size_t ws_size,
                              hipStream_t stream) {
    const float* left  = (const float*)d_in[0];
    const float* right = (const float*)d_in[1];
    const float* rel   = (const float*)d_in[2];
    const float* Wih_l = (const float*)d_in[3];
    const float* Whh_l = (const float*)d_in[4];
    const float* bih_l = (const float*)d_in[5];
    const float* bhh_l = (const float*)d_in[6];
    const float* Wih_r = (const float*)d_in[7];
    const float* Whh_r = (const float*)d_in[8];
    const float* bih_r = (const float*)d_in[9];
    const float* bhh_r = (const float*)d_in[10];
    const float* Wenc  = (const float*)d_in[11];
    const float* benc  = (const float*)d_in[12];
    float* out = (float*)d_out;

    char* ws = (char*)d_ws;
    _Float16* pih_l = (_Float16*)(ws);
    _Float16* phh_l = (_Float16*)(ws + 512 * 1024);
    _Float16* pih_r = (_Float16*)(ws + 1024 * 1024);
    _Float16* phh_r = (_Float16*)(ws + 1536 * 1024);
    _Float16* penc  = (_Float16*)(ws + 2048 * 1024);
    _Float16* rel16 = (_Float16*)(ws + 2560 * 1024);
    _Float16* hl16  = (_Float16*)(ws + 4608 * 1024);
    _Float16* hr16  = (_Float16*)(ws + 4608 * 1024 + 8192 * 1024);
    (void)in_sizes; (void)n_in; (void)out_size; (void)ws_size;

    hipLaunchKernelGGL(prep_kernel, dim3(512), dim3(256), 0, stream,
                       Wih_l, Whh_l, Wih_r, Whh_r, Wenc, rel,
                       pih_l, phh_l, pih_r, phh_r, penc, rel16);

    hipLaunchKernelGGL(lstm_kernel, dim3(N_NODES / 64, 2), dim3(512), 0, stream,
                       left, right, pih_l, phh_l, pih_r, phh_r,
                       bih_l, bhh_l, bih_r, bhh_r, hl16, hr16);

    hipLaunchKernelGGL(enc_kernel, dim3(N_NODES / 64), dim3(256), 0, stream,
                       hl16, hr16, rel16, penc, benc, out);
}

// Round 4
// 1302.466 us; speedup vs baseline: 1.1780x; 1.0754x over previous
//
#include <hip/hip_runtime.h>
#include <hip/hip_fp16.h>

#define N_NODES 16384
#define SEQ_L   8
#define DIM_D   256
#define DIM_H   256
#define DIM_R   64

typedef float    f32x4 __attribute__((ext_vector_type(4)));
typedef _Float16 f16x8 __attribute__((ext_vector_type(8)));
typedef _Float16 f16x4 __attribute__((ext_vector_type(4)));

__device__ __forceinline__ float fsig(float x) {
    return __builtin_amdgcn_rcpf(1.f + __expf(-x));
}
__device__ __forceinline__ float ftanh(float x) {
    return 1.f - 2.f * __builtin_amdgcn_rcpf(1.f + __expf(2.f * x));
}

// ---------------------------------------------------------------------------
// prep: pack lstm weights for the 16-wave consumer:
//   P[w*16384 + (ks*4+g)*512 + lane*8 + j] =
//       W[g*256 + w*16 + (lane&15)][ks*32 + (lane>>4)*8 + j]
// -> per (w,ks): one vaddr (lane*16B), 4 loads at imm {0,1024,2048,3072}B.
// enc weights packed per 4-wave layout: penc[w*36864 + (ct*18+ks)*512 + lane*8].
// ---------------------------------------------------------------------------
__global__ void prep_kernel(const float* __restrict__ Wih_l, const float* __restrict__ Whh_l,
                            const float* __restrict__ Wih_r, const float* __restrict__ Whh_r,
                            const float* __restrict__ Wenc,  const float* __restrict__ rel,
                            _Float16* __restrict__ pih_l, _Float16* __restrict__ phh_l,
                            _Float16* __restrict__ pih_r, _Float16* __restrict__ phh_r,
                            _Float16* __restrict__ penc,  _Float16* __restrict__ rel16) {
    const int stride = gridDim.x * blockDim.x;
    const int t0 = blockIdx.x * blockDim.x + threadIdx.x;

    const float* SW[4] = {Wih_l, Whh_l, Wih_r, Whh_r};
    _Float16*    DW[4] = {pih_l, phh_l, pih_r, phh_r};
    for (int m = 0; m < 4; ++m) {
        const float* W = SW[m];
        _Float16*    P = DW[m];
        for (int i8 = t0; i8 < 32768; i8 += stride) {
            int w    = i8 >> 11;          // wave 0..15
            int rem  = i8 & 2047;
            int f    = rem >> 6;          // 0..31 = ks*4 + g
            int lane = rem & 63;
            int ks   = f >> 2;
            int g    = f & 3;
            int col  = g * 256 + w * 16 + (lane & 15);
            int k    = ks * 32 + (lane >> 4) * 8;
            const float* s = W + (size_t)col * 256 + k;
            f32x4 v0 = *(const f32x4*)s;
            f32x4 v1 = *(const f32x4*)(s + 4);
            f16x8 h;
            h[0] = (_Float16)v0[0]; h[1] = (_Float16)v0[1];
            h[2] = (_Float16)v0[2]; h[3] = (_Float16)v0[3];
            h[4] = (_Float16)v1[0]; h[5] = (_Float16)v1[1];
            h[6] = (_Float16)v1[2]; h[7] = (_Float16)v1[3];
            *(f16x8*)&P[(size_t)i8 * 8] = h;
        }
    }

    // enc: 4 waves x 72 frags (ct*18+ks), Wenc [256][576]
    for (int i8 = t0; i8 < 18432; i8 += stride) {
        int w    = i8 / 4608;
        int rem  = i8 - w * 4608;
        int f    = rem >> 6;
        int lane = rem & 63;
        int ct   = f / 18;
        int ks   = f - ct * 18;
        int col  = w * 64 + ct * 16 + (lane & 15);
        int k    = ks * 32 + (lane >> 4) * 8;
        const float* s = Wenc + (size_t)col * 576 + k;
        f32x4 v0 = *(const f32x4*)s;
        f32x4 v1 = *(const f32x4*)(s + 4);
        f16x8 h;
        h[0] = (_Float16)v0[0]; h[1] = (_Float16)v0[1];
        h[2] = (_Float16)v0[2]; h[3] = (_Float16)v0[3];
        h[4] = (_Float16)v1[0]; h[5] = (_Float16)v1[1];
        h[6] = (_Float16)v1[2]; h[7] = (_Float16)v1[3];
        *(f16x8*)&penc[(size_t)i8 * 8] = h;
    }

    const int nq = (N_NODES * DIM_R) / 8;
    for (int i = t0; i < nq; i += stride) {
        f32x4 v0 = *(const f32x4*)(rel + (size_t)i * 8);
        f32x4 v1 = *(const f32x4*)(rel + (size_t)i * 8 + 4);
        f16x8 h;
        h[0] = (_Float16)v0[0]; h[1] = (_Float16)v0[1];
        h[2] = (_Float16)v0[2]; h[3] = (_Float16)v0[3];
        h[4] = (_Float16)v1[0]; h[5] = (_Float16)v1[1];
        h[6] = (_Float16)v1[2]; h[7] = (_Float16)v1[3];
        *(f16x8*)&rel16[(size_t)i * 8] = h;
    }
}

// ---------------------------------------------------------------------------
// fused LSTM: 32 nodes/block, 1024 threads = 16 waves, 4 waves/SIMD (<=128 reg).
// Wave w owns cols [w*16, w*16+16) of each gate. acc[2 rt][4 g] = 32 regs.
// LDS 32KB: x at 0, h at 8192 (elem). Swizzle: elem (row,k) at
// row*256 + (k ^ ((row&3)<<3)); XOR bits disjoint from ks*32 imm.
// ---------------------------------------------------------------------------
__global__ __launch_bounds__(1024, 4) void lstm_kernel(
    const float* __restrict__ left, const float* __restrict__ right,
    const _Float16* __restrict__ pih_l, const _Float16* __restrict__ phh_l,
    const _Float16* __restrict__ pih_r, const _Float16* __restrict__ phh_r,
    const float* __restrict__ bih_l, const float* __restrict__ bhh_l,
    const float* __restrict__ bih_r, const float* __restrict__ bhh_r,
    _Float16* __restrict__ hl_out, _Float16* __restrict__ hr_out) {

    const int side = blockIdx.y;
    const float*    chain = side ? right : left;
    const float*    bih   = side ? bih_r : bih_l;
    const float*    bhh   = side ? bhh_r : bhh_l;
    _Float16*       hout  = side ? hr_out : hl_out;

    __shared__ _Float16 lds[2 * 32 * 256] __attribute__((aligned(16)));
    const int HOFF = 32 * 256;

    const int tid  = threadIdx.x;
    const int lane = tid & 63;
    const int wave = tid >> 6;        // 0..15
    const int wu   = __builtin_amdgcn_readfirstlane(wave);
    const int l15  = lane & 15;
    const int l4   = lane >> 4;       // 0..3
    const int klb  = l4 * 8;
    const int node0 = blockIdx.x * 32;
    const int hid0  = wu * 16;

    const _Float16* Pih = (side ? pih_r : pih_l) + wu * 16384;
    const _Float16* Phh = (side ? phh_r : phh_l) + wu * 16384;

    const f32x4 FZ = {0.f, 0.f, 0.f, 0.f};

    float bias[4];
#pragma unroll
    for (int g = 0; g < 4; ++g) {
        int col = g * 256 + hid0 + l15;
        bias[g] = bih[col] + bhh[col];
    }

    f32x4 acc[2][4];
    f32x4 cst[2];
    cst[0] = FZ; cst[1] = FZ;

    int abase[2];
#pragma unroll
    for (int rt = 0; rt < 2; ++rt) {
        int row = rt * 16 + l15;
        abase[rt] = row * 256 + (klb ^ ((row & 3) << 3));
    }

    auto do_gemm = [&](const int lds_ofs, const _Float16* Pw) {
#pragma unroll
        for (int ks = 0; ks < 8; ++ks) {
            f16x8 a[2];
#pragma unroll
            for (int rt = 0; rt < 2; ++rt)
                a[rt] = *(const f16x8*)&lds[lds_ofs + abase[rt] + ks * 32];
            f16x8 b[4];
#pragma unroll
            for (int g = 0; g < 4; ++g)
                b[g] = *(const f16x8*)&Pw[(ks * 4 + g) * 512 + (lane << 3)];
#pragma unroll
            for (int g = 0; g < 4; ++g)
#pragma unroll
                for (int rt = 0; rt < 2; ++rt)
                    acc[rt][g] = __builtin_amdgcn_mfma_f32_16x16x32_f16(
                        a[rt], b[g], acc[rt][g], 0, 0, 0);
        }
    };

#pragma unroll 1
    for (int t = 0; t < SEQ_L; ++t) {
        // stage x_t: 32 rows x 64 f32x4, 1024 threads -> 2 iters
#pragma unroll
        for (int it = 0; it < 2; ++it) {
            int e4  = it * 1024 + tid;     // 0..2047
            int row = e4 >> 6;
            int kq  = (e4 & 63) << 2;
            f32x4 v = __builtin_nontemporal_load((const f32x4*)(chain +
                      (size_t)(node0 + row) * (SEQ_L * DIM_D) + t * DIM_D + kq));
            f16x4 h4;
            h4[0] = (_Float16)v[0]; h4[1] = (_Float16)v[1];
            h4[2] = (_Float16)v[2]; h4[3] = (_Float16)v[3];
            *(f16x4*)&lds[row * 256 + (kq ^ ((row & 3) << 3))] = h4;
        }
        __syncthreads();

#pragma unroll
        for (int rt = 0; rt < 2; ++rt)
#pragma unroll
            for (int g = 0; g < 4; ++g) acc[rt][g] = FZ;

        do_gemm(0, Pih);
        if (t > 0) do_gemm(HOFF, Phh);
        __syncthreads();

#pragma unroll
        for (int rt = 0; rt < 2; ++rt)
#pragma unroll
            for (int r = 0; r < 4; ++r) {
                float gi = acc[rt][0][r] + bias[0];
                float gf = acc[rt][1][r] + bias[1];
                float gg = acc[rt][2][r] + bias[2];
                float go = acc[rt][3][r] + bias[3];
                float ii = fsig(gi), ff = fsig(gf);
                float gt = ftanh(gg), oo = fsig(go);
                float c = ff * cst[rt][r] + ii * gt;
                cst[rt][r] = c;
                float h = oo * ftanh(c);
                int rowl = rt * 16 + l4 * 4 + r;
                int hid  = hid0 + l15;
                lds[HOFF + rowl * 256 + (hid ^ ((rowl & 3) << 3))] = (_Float16)h;
            }
    }

    // coalesced copy-out of h(7): 32 rows x 32 f16x8
    __syncthreads();
    {
        int row = tid >> 5;            // 0..31
        int seg = (tid & 31) * 8;      // 0..248
        f16x8 v = *(const f16x8*)&lds[HOFF + row * 256 + (seg ^ ((row & 3) << 3))];
        __builtin_nontemporal_store(v, (f16x8*)(hout + (size_t)(node0 + row) * 256 + seg));
    }
}

// ---------------------------------------------------------------------------
// encoder: tanh([hl|hr|rel] @ Wenc^T + benc), wave-major packed Wenc
// ---------------------------------------------------------------------------
__global__ __launch_bounds__(256, 2) void enc_kernel(
    const _Float16* __restrict__ hl, const _Float16* __restrict__ hr,
    const _Float16* __restrict__ rel16, const _Float16* __restrict__ penc,
    const float* __restrict__ benc, float* __restrict__ out) {

    const int tid  = threadIdx.x;
    const int lane = tid & 63;
    const int wave = tid >> 6;    // 0..3
    const int wu   = __builtin_amdgcn_readfirstlane(wave);
    const int l15  = lane & 15;
    const int l4   = lane >> 4;
    const int klb  = l4 * 8;
    const int row0 = blockIdx.x * 64;
    const int colw = wu * 64;

    const _Float16* Pw = penc + wu * 36864;

    const f32x4 FZ = {0.f, 0.f, 0.f, 0.f};
    f32x4 acc[4][4];
#pragma unroll
    for (int rt = 0; rt < 4; ++rt)
#pragma unroll
        for (int ct = 0; ct < 4; ++ct) acc[rt][ct] = FZ;

    float bce[4];
#pragma unroll
    for (int ct = 0; ct < 4; ++ct) bce[ct] = benc[colw + ct * 16 + l15];

    for (int ks = 0; ks < 18; ++ks) {   // K = 576
        const int kk = ks * 32 + klb;
        f16x8 a[4];
#pragma unroll
        for (int rt = 0; rt < 4; ++rt) {
            int row = row0 + rt * 16 + l15;
            const _Float16* p;
            if (ks < 8)       p = hl    + (size_t)row * 256 + kk;
            else if (ks < 16) p = hr    + (size_t)row * 256 + (kk - 256);
            else              p = rel16 + (size_t)row * 64  + (kk - 512);
            a[rt] = *(const f16x8*)p;
        }
#pragma unroll
        for (int ct = 0; ct < 4; ++ct) {
            f16x8 b = *(const f16x8*)&Pw[(ct * 18 + ks) * 512 + (lane << 3)];
#pragma unroll
            for (int rt = 0; rt < 4; ++rt)
                acc[rt][ct] = __builtin_amdgcn_mfma_f32_16x16x32_f16(
                    a[rt], b, acc[rt][ct], 0, 0, 0);
        }
    }

#pragma unroll
    for (int rt = 0; rt < 4; ++rt)
#pragma unroll
        for (int ct = 0; ct < 4; ++ct)
#pragma unroll
            for (int r = 0; r < 4; ++r) {
                int row = row0 + rt * 16 + l4 * 4 + r;
                int col = colw + ct * 16 + l15;
                out[(size_t)row * 256 + col] = ftanh(acc[rt][ct][r] + bce[ct]);
            }
}

extern "C" void kernel_launch(void* const* d_in, const int* in_sizes, int n_in,
                              void* d_out, int out_size, void* d_ws, size_t ws_size,
                              hipStream_t stream) {
    const float* left  = (const float*)d_in[0];
    const float* right = (const float*)d_in[1];
    const float* rel   = (const float*)d_in[2];
    const float* Wih_l = (const float*)d_in[3];
    const float* Whh_l = (const float*)d_in[4];
    const float* bih_l = (const float*)d_in[5];
    const float* bhh_l = (const float*)d_in[6];
    const float* Wih_r = (const float*)d_in[7];
    const float* Whh_r = (const float*)d_in[8];
    const float* bih_r = (const float*)d_in[9];
    const float* bhh_r = (const float*)d_in[10];
    const float* Wenc  = (const float*)d_in[11];
    const float* benc  = (const float*)d_in[12];
    float* out = (float*)d_out;

    char* ws = (char*)d_ws;
    _Float16* pih_l = (_Float16*)(ws);
    _Float16* phh_l = (_Float16*)(ws + 512 * 1024);
    _Float16* pih_r = (_Float16*)(ws + 1024 * 1024);
    _Float16* phh_r = (_Float16*)(ws + 1536 * 1024);
    _Float16* penc  = (_Float16*)(ws + 2048 * 1024);
    _Float16* rel16 = (_Float16*)(ws + 2560 * 1024);
    _Float16* hl16  = (_Float16*)(ws + 4608 * 1024);
    _Float16* hr16  = (_Float16*)(ws + 4608 * 1024 + 8192 * 1024);
    (void)in_sizes; (void)n_in; (void)out_size; (void)ws_size;

    hipLaunchKernelGGL(prep_kernel, dim3(512), dim3(256), 0, stream,
                       Wih_l, Whh_l, Wih_r, Whh_r, Wenc, rel,
                       pih_l, phh_l, pih_r, phh_r, penc, rel16);

    hipLaunchKernelGGL(lstm_kernel, dim3(N_NODES / 32, 2), dim3(1024), 0, stream,
                       left, right, pih_l, phh_l, pih_r, phh_r,
                       bih_l, bhh_l, bih_r, bhh_r, hl16, hr16);

    hipLaunchKernelGGL(enc_kernel, dim3(N_NODES / 64), dim3(256), 0, stream,
                       hl16, hr16, rel16, penc, benc, out);
}